// Round 9
// baseline (224.897 us; speedup 1.0000x reference)
//
#include <hip/hip_runtime.h>
#include <hip/hip_bf16.h>
#include <stdint.h>

// B=2, S=2048, E=1024, H=16, D=64.
// d_out (fp32): out [2,2048,1024] then probs [2,16,2048,2048].
// d_ws (shorts): Xb | Wt(q,k,v,o transposed) | Q | K | V | ctx  (each 4,194,304).

typedef __attribute__((ext_vector_type(8))) short bf16x8;
typedef __attribute__((ext_vector_type(4))) short bf16x4v;
typedef __attribute__((ext_vector_type(4))) float f32x4;

#define DEV static __device__ __forceinline__

DEV short f2bs(float f) {
  union { __hip_bfloat16 b; short s; } u;
  u.b = __float2bfloat16(f);
  return u.s;
}
DEV f32x4 mfma16(bf16x8 a, bf16x8 b, f32x4 c) {
  return __builtin_amdgcn_mfma_f32_16x16x32_bf16(a, b, c, 0, 0, 0);
}
DEV float fexp2(float x) { return __builtin_amdgcn_exp2f(x); }
typedef const __attribute__((address_space(1))) void* gas1_t;
typedef __attribute__((address_space(3))) void* las3_t;
DEV void gload_lds16(const void* g, void* l) {
  // LDS dest is wave-uniform base + lane*16; global src is per-lane.
  __builtin_amdgcn_global_load_lds((gas1_t)(uintptr_t)g, (las3_t)(uint32_t)(uintptr_t)l,
                                   16, 0, 0);
}
#define WAIT_VMCNT(N) asm volatile("s_waitcnt vmcnt(" #N ")" ::: "memory")
#define WAIT_LGKM0() asm volatile("s_waitcnt lgkmcnt(0)" ::: "memory")
#define BARRIER() do { __builtin_amdgcn_s_barrier(); __builtin_amdgcn_sched_barrier(0); } while (0)

// ---------- fused converts: X fp32->bf16, W [k][n] fp32 -> Wt [mat][n][k] bf16 ----------
__global__ void cvt_all_kernel(const float* __restrict__ X,
                               const float* __restrict__ Wq, const float* __restrict__ Wk,
                               const float* __restrict__ Wv, const float* __restrict__ Wo,
                               short* __restrict__ Xb, short* __restrict__ Wt) {
  __shared__ short tile[64][68];
  int bx = blockIdx.x, t = threadIdx.x;
  if (bx < 2048) {
    size_t i = (size_t)bx * 256 + t;
    const float4* X4 = (const float4*)X;
    float4 a = X4[2 * i], c = X4[2 * i + 1];
    bf16x8 o;
    o[0] = f2bs(a.x); o[1] = f2bs(a.y); o[2] = f2bs(a.z); o[3] = f2bs(a.w);
    o[4] = f2bs(c.x); o[5] = f2bs(c.y); o[6] = f2bs(c.z); o[7] = f2bs(c.w);
    *(bf16x8*)(Xb + i * 8) = o;
    return;
  }
  int wb = bx - 2048;
  int mat = wb >> 8, rem = wb & 255;
  const float* W = mat == 0 ? Wq : mat == 1 ? Wk : mat == 2 ? Wv : Wo;
  int kb = (rem >> 4) * 64, nb = (rem & 15) * 64;
#pragma unroll
  for (int it = 0; it < 4; ++it) {
    int idx = it * 256 + t;
    int row = idx >> 4, c4 = (idx & 15) * 4;
    float4 v = *(const float4*)(W + (size_t)(kb + row) * 1024 + nb + c4);
    tile[row][c4 + 0] = f2bs(v.x); tile[row][c4 + 1] = f2bs(v.y);
    tile[row][c4 + 2] = f2bs(v.z); tile[row][c4 + 3] = f2bs(v.w);
  }
  __syncthreads();
#pragma unroll
  for (int it = 0; it < 4; ++it) {
    int idx = it * 256 + t;
    int rn = idx >> 4, c4 = (idx & 15) * 4;
    bf16x4v o;
    o[0] = tile[c4 + 0][rn]; o[1] = tile[c4 + 1][rn];
    o[2] = tile[c4 + 2][rn]; o[3] = tile[c4 + 3][rn];
    *(bf16x4v*)(Wt + (((size_t)mat) << 20) + (size_t)(nb + rn) * 1024 + kb + c4) = o;
  }
}

// ---------- GEMM: A[M][1024] bf16 @ Bt[N][1024] bf16, 128^2 tile, BK=32 ----------
template <int MODE, int GBX>
__global__ __launch_bounds__(256, 2)
void gemm_bt_kernel(const short* __restrict__ A, const short* __restrict__ Bt,
                    const float* __restrict__ bias0, const float* __restrict__ bias1,
                    const float* __restrict__ bias2,
                    short* __restrict__ o0, short* __restrict__ o1, short* __restrict__ o2,
                    float* __restrict__ fout) {
  __shared__ short As[2][128 * 32];
  __shared__ short Bs[2][128 * 32];
  const int nwg = GBX * gridDim.y;
  const int cpx = nwg >> 3;  // nwg % 8 == 0 for our grids
  const int bid0 = blockIdx.y * GBX + blockIdx.x;
  const int bid = (bid0 % 8) * cpx + bid0 / 8;  // bijective XCD swizzle
  const int m0 = (bid % GBX) * 128, n0 = (bid / GBX) * 128;
  const int t = threadIdx.x, w = t >> 6, l = t & 63, g = l >> 4, r = l & 15;
  const int wr = (w >> 1) * 64, wc = (w & 1) * 64;
  f32x4 acc[4][4] = {};

#define STAGE_G(k0_, b_)                                                                   \
  do {                                                                                     \
    gload_lds16(A + (size_t)(m0 + (t >> 2)) * 1024 + (k0_) + (t & 3) * 8, As[b_] + w * 512); \
    gload_lds16(A + (size_t)(m0 + 64 + (t >> 2)) * 1024 + (k0_) + (t & 3) * 8,             \
                As[b_] + 2048 + w * 512);                                                  \
    gload_lds16(Bt + (size_t)(n0 + (t >> 2)) * 1024 + (k0_) + (t & 3) * 8, Bs[b_] + w * 512); \
    gload_lds16(Bt + (size_t)(n0 + 64 + (t >> 2)) * 1024 + (k0_) + (t & 3) * 8,            \
                Bs[b_] + 2048 + w * 512);                                                  \
  } while (0)

  STAGE_G(0, 0);
  for (int it = 0; it < 32; ++it) {
    const int cur = it & 1;
    if (it < 31) {
      STAGE_G((it + 1) * 32, cur ^ 1);
      WAIT_VMCNT(4);
    } else {
      WAIT_VMCNT(0);
    }
    BARRIER();
    bf16x8 af[4], bfv[4];
#pragma unroll
    for (int i = 0; i < 4; i++) af[i] = *(const bf16x8*)(As[cur] + (wr + i * 16 + r) * 32 + g * 8);
#pragma unroll
    for (int j = 0; j < 4; j++) bfv[j] = *(const bf16x8*)(Bs[cur] + (wc + j * 16 + r) * 32 + g * 8);
    __builtin_amdgcn_s_setprio(1);
#pragma unroll
    for (int i = 0; i < 4; i++)
#pragma unroll
      for (int j = 0; j < 4; j++) acc[i][j] = mfma16(af[i], bfv[j], acc[i][j]);
    __builtin_amdgcn_s_setprio(0);
    BARRIER();
  }
#undef STAGE_G
  if constexpr (MODE == 0) {
#pragma unroll
    for (int j = 0; j < 4; j++) {
      int ng = n0 + wc + j * 16 + r;
      int mat = ng >> 10, nn = ng & 1023, hh = nn >> 6, dd = nn & 63;
      const float* bp = mat == 0 ? bias0 : (mat == 1 ? bias1 : bias2);
      short* dst = mat == 0 ? o0 : (mat == 1 ? o1 : o2);
      float bv = bp[nn];
      float sc = (mat == 0) ? 0.18033688f : 1.0f;  // 1/sqrt(D) * log2(e) folded into Q
#pragma unroll
      for (int i = 0; i < 4; i++) {
#pragma unroll
        for (int q = 0; q < 4; q++) {
          int m = m0 + wr + i * 16 + g * 4 + q;
          int bb = m >> 11, ss = m & 2047;
          dst[((size_t)(bb * 16 + hh) * 2048 + ss) * 64 + dd] = f2bs((acc[i][j][q] + bv) * sc);
        }
      }
    }
  } else {
#pragma unroll
    for (int i = 0; i < 4; i++)
#pragma unroll
      for (int q = 0; q < 4; q++) {
        int m = m0 + wr + i * 16 + g * 4 + q;
#pragma unroll
        for (int j = 0; j < 4; j++) {
          int ng = n0 + wc + j * 16 + r;
          fout[(size_t)m * 1024 + ng] = acc[i][j][q] + bias0[ng];
        }
      }
  }
}

// ---------- fused attention: 2 q-tiles/block, KVBLK=128, 1-deep pipelined B-loops ----------
// Loop1: A(tile0). Loop2: B(tile0)+A(tile1). Loop3: B(tile1).
// B-loops software-pipelined one iter deep: iter kt computes QK^T(kt) and FINISHES
// kt-1 (probs stores + PV) in the MFMA shadow; Vt/Ps for kt written at the iter tail
// (read by PV only next iter, fenced by the top barrier).
// vmcnt ledger (ops newer than the waited-for group, counted per issue order):
//   top wait  — kt=0: 8 (V0:4+S1:4); kt=1: 8 (no FIN stores in iter0); steady: 16
//               (FINst:8+V:4+S:4); last: 12 (FINst:8+V:4).
//   tail wait — kt=0: 4 (S1); kt=1..14: 12 (S:4+FINst:8); last: 8 (FINst:8).
__global__ __launch_bounds__(256, 2)
void attn_kernel(const short* __restrict__ Qm, const short* __restrict__ Km,
                 const short* __restrict__ Vm, float* __restrict__ probs,
                 short* __restrict__ ctx) {
  __shared__ short Ks[2][128 * 64];  // K tiles (32 KB); Q0/Q1 staged here in prologue
  __shared__ short Vt[64 * 136];     // V^T [64 d][128 k + pad], 8-short-unit XOR swizzle
  __shared__ short Ps[4][16 * 136];  // per-wave P bf16 [16 q][128 k] in MFMA-A layout
  __shared__ float rls[128];         // 1/l per q-row (ctx epilogue; [64..127] = tile1)
  const int f = blockIdx.x;
  const int wgid = (f & 7) * 64 + (f >> 3);      // bijective XCD swizzle (nwg=512)
  const int bh = wgid >> 4, q0 = (wgid & 15) * 128;
  const int bb = bh >> 4, hh = bh & 15;
  const short* Qp = Qm + (size_t)bh * 2048 * 64;
  const short* Kp = Km + (size_t)bh * 2048 * 64;
  const short* Vp = Vm + (size_t)bh * 2048 * 64;
  float* Pp = probs + (size_t)bh * 2048 * 2048;
  const int t = threadIdx.x, w = t >> 6, l = t & 63, g = l >> 4, r = l & 15;
  const int lr = l >> 3, lc = l & 7;
  const int swz = lc ^ lr;  // 16B-unit source swizzle for K/Q staging

#define STAGE_K(kt_, buf_)                                                            \
  do {                                                                                \
    const short* src_ = Kp + (size_t)((kt_) * 128) * 64;                              \
    _Pragma("unroll") for (int it_ = 0; it_ < 4; ++it_)                               \
        gload_lds16(src_ + (size_t)(it_ * 32 + w * 8 + lr) * 64 + swz * 8,            \
                    Ks[buf_] + (it_ * 32 + w * 8) * 64);                              \
  } while (0)

  // ---- prologue: stage Q0 -> Ks[0], Q1 -> Ks[1]; hoist both tiles' fragments ----
#pragma unroll
  for (int it = 0; it < 2; ++it) {
    gload_lds16(Qp + (size_t)(q0 + it * 32 + w * 8 + lr) * 64 + swz * 8,
                Ks[0] + (it * 32 + w * 8) * 64);
    gload_lds16(Qp + (size_t)(q0 + 64 + it * 32 + w * 8 + lr) * 64 + swz * 8,
                Ks[1] + (it * 32 + w * 8) * 64);
  }
  __syncthreads();
  bf16x8 qf0[2], qf1[2];
#pragma unroll
  for (int df = 0; df < 2; df++) {
    qf0[df] = *(const bf16x8*)(Ks[0] + (w * 16 + r) * 64 + ((df * 4 + g) ^ (r & 7)) * 8);
    qf1[df] = *(const bf16x8*)(Ks[1] + (w * 16 + r) * 64 + ((df * 4 + g) ^ (r & 7)) * 8);
  }
  WAIT_LGKM0();
  BARRIER();  // fragments in regs; Ks buffers free

  // -------- loop 1: A(tile0) — row sums of exp2(s), 16 iters --------
  float lrow0 = 0.f;
  STAGE_K(0, 0);
  for (int kt = 0; kt < 16; ++kt) {
    const int cur = kt & 1;
    if (kt < 15) {
      STAGE_K(kt + 1, cur ^ 1);
      WAIT_VMCNT(4);
    } else {
      WAIT_VMCNT(0);
    }
    BARRIER();
    f32x4 st[8] = {};
    __builtin_amdgcn_s_setprio(1);
#pragma unroll
    for (int df = 0; df < 2; ++df) {
      bf16x8 kf[8];
#pragma unroll
      for (int ni = 0; ni < 8; ni++)
        kf[ni] = *(const bf16x8*)(Ks[cur] + (ni * 16 + r) * 64 + ((df * 4 + g) ^ (r & 7)) * 8);
#pragma unroll
      for (int ni = 0; ni < 8; ni++) st[ni] = mfma16(kf[ni], qf0[df], st[ni]);
    }
    __builtin_amdgcn_s_setprio(0);
    float ssum = 0.f;
#pragma unroll
    for (int ni = 0; ni < 8; ni++)
#pragma unroll
      for (int q4 = 0; q4 < 4; q4++) ssum += fexp2(st[ni][q4]);
    ssum += __shfl_xor(ssum, 16);
    ssum += __shfl_xor(ssum, 32);
    lrow0 += ssum;
    BARRIER();  // all waves done reading Ks[cur] before next STAGE overwrites
  }
  const float rinv0 = 1.0f / lrow0;
  if (g == 0) rls[w * 16 + r] = rinv0;

  // V-transpose helper indices
  const int kp = (t >> 3) * 2, d0v = (t & 7) * 8, lcv = t & 7, kunit = t >> 5;

#define V_LOADS(kt_)                                                                   \
  v0 = *(const bf16x8*)(Vp + (size_t)((kt_) * 128 + kp) * 64 + d0v);                   \
  v1 = *(const bf16x8*)(Vp + (size_t)((kt_) * 128 + kp + 1) * 64 + d0v);               \
  v2 = *(const bf16x8*)(Vp + (size_t)((kt_) * 128 + 64 + kp) * 64 + d0v);              \
  v3 = *(const bf16x8*)(Vp + (size_t)((kt_) * 128 + 64 + kp + 1) * 64 + d0v)

  // FIN(ktF): probs stores from stP (exp'd fp32) + PV from Ps/Vt (ktF data)
#define FIN_T(stP_, qrow_, rinv_, ktF_)                                                \
  do {                                                                                 \
    _Pragma("unroll") for (int ni = 0; ni < 8; ni++) {                                 \
      f32x4 pr;                                                                        \
      _Pragma("unroll") for (int q4 = 0; q4 < 4; q4++) pr[q4] = (stP_)[ni][q4] * (rinv_); \
      *(f32x4*)(Pp + (size_t)((qrow_) + w * 16 + r) * 2048 + (ktF_) * 128 + ni * 16 + g * 4) = pr; \
    }                                                                                  \
    __builtin_amdgcn_s_setprio(1);                                                     \
    _Pragma("unroll") for (int kf4 = 0; kf4 < 4; ++kf4) {                              \
      bf16x8 pa, vb[4];                                                                \
      pa = *(const bf16x8*)(&Ps[w][r * 136 + kf4 * 32 + g * 8]);                       \
      _Pragma("unroll") for (int nj = 0; nj < 4; nj++) {                               \
        int u_ = kf4 * 4 + g, x_ = nj * 2 + (r >> 3);                                  \
        int su_ = (u_ & 8) | ((u_ & 7) ^ x_);                                          \
        vb[nj] = *(const bf16x8*)(Vt + (nj * 16 + r) * 136 + (su_ << 3));              \
      }                                                                                \
      _Pragma("unroll") for (int nj = 0; nj < 4; nj++)                                 \
          cacc[nj] = mfma16(pa, vb[nj], cacc[nj]);                                     \
    }                                                                                  \
    __builtin_amdgcn_s_setprio(0);                                                     \
  } while (0)

  // One pipelined B-iter. stC_: current scores; stP_: previous iter's exp'd scores.
#define B_ITER(kt_, stC_, stP_, HAS_FIN, FIRST, SECOND, LAST, T1, qf_, qrow_, rinv_)   \
  do {                                                                                 \
    const int cur_ = (kt_) & 1;                                                        \
    bf16x4v pk[8];                                                                     \
    V_LOADS(kt_);                                                                      \
    if (!(LAST)) STAGE_K((kt_) + 1, cur_ ^ 1);                                         \
    if ((FIRST) || (SECOND)) { WAIT_VMCNT(8); }                                        \
    else if (LAST) { WAIT_VMCNT(12); }                                                 \
    else { WAIT_VMCNT(16); }                                                           \
    BARRIER();                                                                         \
    __builtin_amdgcn_s_setprio(1);                                                     \
    _Pragma("unroll") for (int df = 0; df < 2; ++df) {                                 \
      bf16x8 kf[8];                                                                    \
      _Pragma("unroll") for (int ni = 0; ni < 8; ni++)                                 \
          kf[ni] = *(const bf16x8*)(Ks[cur_] + (ni * 16 + r) * 64 +                    \
                                    ((df * 4 + g) ^ (r & 7)) * 8);                     \
      _Pragma("unroll") for (int ni = 0; ni < 8; ni++) {                               \
        (stC_)[ni] = mfma16(kf[ni], qf_[df], (stC_)[ni]);                              \
        if (T1) st1[ni] = mfma16(kf[ni], qf1[df], st1[ni]);                            \
      }                                                                                \
    }                                                                                  \
    __builtin_amdgcn_s_setprio(0);                                                     \
    if (HAS_FIN) FIN_T(stP_, qrow_, rinv_, (kt_)-1);                                   \
    _Pragma("unroll") for (int ni = 0; ni < 8; ni++) {                                 \
      _Pragma("unroll") for (int q4 = 0; q4 < 4; q4++) {                               \
        float pe = fexp2((stC_)[ni][q4]);                                              \
        (stC_)[ni][q4] = pe;                                                           \
        pk[ni][q4] = f2bs(pe);                                                         \
      }                                                                                \
    }                                                                                  \
    if (T1) {                                                                          \
      float ssum = 0.f;                                                                \
      _Pragma("unroll") for (int ni = 0; ni < 8; ni++)                                 \
          _Pragma("unroll") for (int q4 = 0; q4 < 4; q4++) ssum += fexp2(st1[ni][q4]); \
      ssum += __shfl_xor(ssum, 16);                                                    \
      ssum += __shfl_xor(ssum, 32);                                                    \
      lrow1 += ssum;                                                                   \
    }                                                                                  \
    BARRIER();                                                                         \
    if (FIRST) { WAIT_VMCNT(4); }                                                      \
    else if (LAST) { WAIT_VMCNT(8); }                                                  \
    else { WAIT_VMCNT(12); }                                                           \
    _Pragma("unroll") for (int e = 0; e < 8; e++) {                                    \
      unsigned int p0_ = (unsigned int)(unsigned short)v0[e] |                         \
                         ((unsigned int)(unsigned short)v1[e] << 16);                  \
      unsigned int p1_ = (unsigned int)(unsigned short)v2[e] |                         \
                         ((unsigned int)(unsigned short)v3[e] << 16);                  \
      *(unsigned int*)(Vt + (d0v + e) * 136 + ((kunit ^ lcv) << 3) + (kp & 7)) = p0_;  \
      *(unsigned int*)(Vt + (d0v + e) * 136 + ((8 + (kunit ^ lcv)) << 3) + (kp & 7)) = p1_; \
    }                                                                                  \
    _Pragma("unroll") for (int ni = 0; ni < 8; ni++)                                   \
        *(bf16x4v*)(&Ps[w][r * 136 + ni * 16 + g * 4]) = pk[ni];                       \
    WAIT_LGKM0();                                                                      \
  } while (0)

  // -------- loop 2: B(tile0) fused with A(tile1), pipelined --------
  f32x4 cacc[4] = {};
  float lrow1 = 0.f;
  {
    bf16x8 v0, v1, v2, v3;
    f32x4 stA[8], stB[8], st1z[8];
    f32x4* st1 = st1z;
    STAGE_K(0, 0);
    for (int i2 = 0; i2 < 8; ++i2) {
#pragma unroll
      for (int ni = 0; ni < 8; ni++) stA[ni] = (f32x4){0.f, 0.f, 0.f, 0.f};
#pragma unroll
      for (int ni = 0; ni < 8; ni++) st1[ni] = (f32x4){0.f, 0.f, 0.f, 0.f};
      if (i2 == 0) {
        B_ITER(0, stA, stB, false, true, false, false, true, qf0, q0, rinv0);
      } else {
        B_ITER(2 * i2, stA, stB, true, false, false, false, true, qf0, q0, rinv0);
      }
#pragma unroll
      for (int ni = 0; ni < 8; ni++) stB[ni] = (f32x4){0.f, 0.f, 0.f, 0.f};
#pragma unroll
      for (int ni = 0; ni < 8; ni++) st1[ni] = (f32x4){0.f, 0.f, 0.f, 0.f};
      B_ITER(2 * i2 + 1, stB, stA, true, false, (i2 == 0), (i2 == 7), true,
             qf0, q0, rinv0);
    }
    // epilogue: finish kt=15 (stB holds its exp'd scores; Vt/Ps hold kt=15 data)
    BARRIER();
    FIN_T(stB, q0, rinv0, 15);
  }
  // ctx epilogue tile0
#pragma unroll
  for (int nj = 0; nj < 4; nj++)
#pragma unroll
    for (int q4 = 0; q4 < 4; q4++) {
      int qt = w * 16 + g * 4 + q4;
      float val = cacc[nj][q4] * rls[qt];
      ctx[((size_t)(bb * 2048 + q0 + qt)) * 1024 + hh * 64 + nj * 16 + r] = f2bs(val);
    }

  // -------- loop 3: B(tile1), pipelined --------
  const float rinv1 = 1.0f / lrow1;
  if (g == 0) rls[64 + w * 16 + r] = rinv1;
#pragma unroll
  for (int nj = 0; nj < 4; nj++) cacc[nj] = (f32x4){0.f, 0.f, 0.f, 0.f};
  {
    bf16x8 v0, v1, v2, v3;
    f32x4 stA[8], stB[8];
    f32x4* st1 = nullptr;  // T1=false paths compiled out
    STAGE_K(0, 0);
    for (int i2 = 0; i2 < 8; ++i2) {
#pragma unroll
      for (int ni = 0; ni < 8; ni++) stA[ni] = (f32x4){0.f, 0.f, 0.f, 0.f};
      if (i2 == 0) {
        B_ITER(0, stA, stB, false, true, false, false, false, qf1, q0 + 64, rinv1);
      } else {
        B_ITER(2 * i2, stA, stB, true, false, false, false, false, qf1, q0 + 64, rinv1);
      }
#pragma unroll
      for (int ni = 0; ni < 8; ni++) stB[ni] = (f32x4){0.f, 0.f, 0.f, 0.f};
      B_ITER(2 * i2 + 1, stB, stA, true, false, (i2 == 0), (i2 == 7), false,
             qf1, q0 + 64, rinv1);
    }
    BARRIER();
    FIN_T(stB, q0 + 64, rinv1, 15);
    (void)st1;
  }
  // ctx epilogue tile1
#pragma unroll
  for (int nj = 0; nj < 4; nj++)
#pragma unroll
    for (int q4 = 0; q4 < 4; q4++) {
      int qt = w * 16 + g * 4 + q4;
      float val = cacc[nj][q4] * rls[64 + qt];
      ctx[((size_t)(bb * 2048 + q0 + 64 + qt)) * 1024 + hh * 64 + nj * 16 + r] = f2bs(val);
    }
#undef B_ITER
#undef FIN_T
#undef V_LOADS
#undef STAGE_K
}

extern "C" void kernel_launch(void* const* d_in, const int* in_sizes, int n_in,
                              void* d_out, int out_size, void* d_ws, size_t ws_size,
                              hipStream_t stream) {
  (void)in_sizes; (void)n_in; (void)out_size; (void)ws_size;
  const float* X  = (const float*)d_in[0];
  const float* Wq = (const float*)d_in[1];
  const float* bq = (const float*)d_in[2];
  const float* Wk = (const float*)d_in[3];
  const float* bk = (const float*)d_in[4];
  const float* Wv = (const float*)d_in[5];
  const float* bv = (const float*)d_in[6];
  const float* Wo = (const float*)d_in[7];
  const float* bo = (const float*)d_in[8];
  float* out = (float*)d_out;
  float* probs = out + (size_t)2 * 2048 * 1024;

  short* Xb = (short*)d_ws;                 // 4096x1024
  short* Wt = Xb + (size_t)4194304;         // 4x1024x1024 (q,k,v,o transposed)
  short* Qb = Wt + (size_t)4194304;         // [B,H,S,D]
  short* Kb = Qb + (size_t)4194304;
  short* Vb = Kb + (size_t)4194304;
  short* Cx = Vb + (size_t)4194304;         // ctx [B,S,E]

  cvt_all_kernel<<<3072, 256, 0, stream>>>(X, Wq, Wk, Wv, Wo, Xb, Wt);
  gemm_bt_kernel<0, 32><<<dim3(32, 24), 256, 0, stream>>>(Xb, Wt, bq, bk, bv,
                                                          Qb, Kb, Vb, nullptr);
  attn_kernel<<<512, 256, 0, stream>>>(Qb, Kb, Vb, probs, Cx);
  gemm_bt_kernel<1, 32><<<dim3(32, 8), 256, 0, stream>>>(Cx, Wt + (size_t)3 * 1048576, bo,
                                                         nullptr, nullptr, nullptr, nullptr,
                                                         nullptr, out);
}

// Round 10
// 212.463 us; speedup vs baseline: 1.0585x; 1.0585x over previous
//
#include <hip/hip_runtime.h>
#include <hip/hip_bf16.h>
#include <stdint.h>

// B=2, S=2048, E=1024, H=16, D=64.
// d_out (fp32): out [2,2048,1024] then probs [2,16,2048,2048].
// d_ws (shorts): Xb | Wt(q,k,v,o transposed) | Q | K | V | ctx  (each 4,194,304).

typedef __attribute__((ext_vector_type(8))) short bf16x8;
typedef __attribute__((ext_vector_type(4))) short bf16x4v;
typedef __attribute__((ext_vector_type(4))) float f32x4;

#define DEV static __device__ __forceinline__

DEV short f2bs(float f) {
  union { __hip_bfloat16 b; short s; } u;
  u.b = __float2bfloat16(f);
  return u.s;
}
DEV f32x4 mfma16(bf16x8 a, bf16x8 b, f32x4 c) {
  return __builtin_amdgcn_mfma_f32_16x16x32_bf16(a, b, c, 0, 0, 0);
}
DEV float fexp2(float x) { return __builtin_amdgcn_exp2f(x); }
typedef const __attribute__((address_space(1))) void* gas1_t;
typedef __attribute__((address_space(3))) void* las3_t;
DEV void gload_lds16(const void* g, void* l) {
  // LDS dest is wave-uniform base + lane*16; global src is per-lane.
  __builtin_amdgcn_global_load_lds((gas1_t)(uintptr_t)g, (las3_t)(uint32_t)(uintptr_t)l,
                                   16, 0, 0);
}
#define WAIT_VMCNT(N) asm volatile("s_waitcnt vmcnt(" #N ")" ::: "memory")
#define WAIT_LGKM0() asm volatile("s_waitcnt lgkmcnt(0)" ::: "memory")
#define BARRIER() do { __builtin_amdgcn_s_barrier(); __builtin_amdgcn_sched_barrier(0); } while (0)

// ---------- fused converts: X fp32->bf16, W [k][n] fp32 -> Wt [mat][n][k] bf16 ----------
__global__ void cvt_all_kernel(const float* __restrict__ X,
                               const float* __restrict__ Wq, const float* __restrict__ Wk,
                               const float* __restrict__ Wv, const float* __restrict__ Wo,
                               short* __restrict__ Xb, short* __restrict__ Wt) {
  __shared__ short tile[64][68];
  int bx = blockIdx.x, t = threadIdx.x;
  if (bx < 2048) {
    size_t i = (size_t)bx * 256 + t;
    const float4* X4 = (const float4*)X;
    float4 a = X4[2 * i], c = X4[2 * i + 1];
    bf16x8 o;
    o[0] = f2bs(a.x); o[1] = f2bs(a.y); o[2] = f2bs(a.z); o[3] = f2bs(a.w);
    o[4] = f2bs(c.x); o[5] = f2bs(c.y); o[6] = f2bs(c.z); o[7] = f2bs(c.w);
    *(bf16x8*)(Xb + i * 8) = o;
    return;
  }
  int wb = bx - 2048;
  int mat = wb >> 8, rem = wb & 255;
  const float* W = mat == 0 ? Wq : mat == 1 ? Wk : mat == 2 ? Wv : Wo;
  int kb = (rem >> 4) * 64, nb = (rem & 15) * 64;
#pragma unroll
  for (int it = 0; it < 4; ++it) {
    int idx = it * 256 + t;
    int row = idx >> 4, c4 = (idx & 15) * 4;
    float4 v = *(const float4*)(W + (size_t)(kb + row) * 1024 + nb + c4);
    tile[row][c4 + 0] = f2bs(v.x); tile[row][c4 + 1] = f2bs(v.y);
    tile[row][c4 + 2] = f2bs(v.z); tile[row][c4 + 3] = f2bs(v.w);
  }
  __syncthreads();
#pragma unroll
  for (int it = 0; it < 4; ++it) {
    int idx = it * 256 + t;
    int rn = idx >> 4, c4 = (idx & 15) * 4;
    bf16x4v o;
    o[0] = tile[c4 + 0][rn]; o[1] = tile[c4 + 1][rn];
    o[2] = tile[c4 + 2][rn]; o[3] = tile[c4 + 3][rn];
    *(bf16x4v*)(Wt + (((size_t)mat) << 20) + (size_t)(nb + rn) * 1024 + kb + c4) = o;
  }
}

// ---------- GEMM: A[M][1024] bf16 @ Bt[N][1024] bf16, BK=64, XOR-swizzled LDS ----------
// MODE 0: 128x128 tile (QKV proj). MODE 1: 128x64 tile (out proj, 2-3 blocks/CU).
// Staging: [row][64] linear LDS via global_load_lds with source col-unit XOR (unit^row&7);
// fragment reads XOR the same way -> 2-way bank aliasing (free). 2 barriers per 64-K.
template <int MODE, int GBX>
__global__ __launch_bounds__(256, MODE == 0 ? 2 : 3)
void gemm_bt_kernel(const short* __restrict__ A, const short* __restrict__ Bt,
                    const float* __restrict__ bias0, const float* __restrict__ bias1,
                    const float* __restrict__ bias2,
                    short* __restrict__ o0, short* __restrict__ o1, short* __restrict__ o2,
                    float* __restrict__ fout) {
  constexpr int BN = (MODE == 0) ? 128 : 64;
  constexpr int NBLINES = BN / 32;
  __shared__ short As[2][128 * 64];
  __shared__ short Bs[2][BN * 64];
  const int nwg = GBX * gridDim.y;
  const int cpx = nwg >> 3;  // nwg % 8 == 0 for our grids
  const int bid0 = blockIdx.y * GBX + blockIdx.x;
  const int bid = (bid0 % 8) * cpx + bid0 / 8;  // bijective XCD swizzle
  const int m0 = (bid % GBX) * 128, n0 = (bid / GBX) * BN;
  const int t = threadIdx.x, w = t >> 6, l = t & 63, g = l >> 4, r = l & 15;
  const int lr = l >> 3, lc = l & 7;
  const int swz = lc ^ lr;  // source col-unit XOR (row&7 == lr at our staging bases)
  const int wr = (w >> 1) * 64, wc = (w & 1) * (BN / 2);
  f32x4 acc[4][BN / 32] = {};

#define STAGE_G(k0_, b_)                                                                \
  do {                                                                                  \
    _Pragma("unroll") for (int it_ = 0; it_ < 4; ++it_)                                 \
        gload_lds16(A + (size_t)(m0 + it_ * 32 + w * 8 + lr) * 1024 + (k0_) + swz * 8,  \
                    As[b_] + (it_ * 32 + w * 8) * 64);                                  \
    _Pragma("unroll") for (int it_ = 0; it_ < NBLINES; ++it_)                           \
        gload_lds16(Bt + (size_t)(n0 + it_ * 32 + w * 8 + lr) * 1024 + (k0_) + swz * 8, \
                    Bs[b_] + (it_ * 32 + w * 8) * 64);                                  \
  } while (0)

  STAGE_G(0, 0);
  for (int it = 0; it < 16; ++it) {
    const int cur = it & 1;
    if (it < 15) {
      STAGE_G((it + 1) * 64, cur ^ 1);
      if constexpr (MODE == 0) { WAIT_VMCNT(8); } else { WAIT_VMCNT(6); }
    } else {
      WAIT_VMCNT(0);
    }
    BARRIER();
    bf16x8 af[2][4], bfv[2][BN / 32];
#pragma unroll
    for (int df = 0; df < 2; df++) {
#pragma unroll
      for (int i = 0; i < 4; i++)
        af[df][i] = *(const bf16x8*)(As[cur] + (wr + i * 16 + r) * 64 +
                                     ((df * 4 + g) ^ (r & 7)) * 8);
#pragma unroll
      for (int j = 0; j < BN / 32; j++)
        bfv[df][j] = *(const bf16x8*)(Bs[cur] + (wc + j * 16 + r) * 64 +
                                      ((df * 4 + g) ^ (r & 7)) * 8);
    }
    __builtin_amdgcn_s_setprio(1);
#pragma unroll
    for (int df = 0; df < 2; df++)
#pragma unroll
      for (int i = 0; i < 4; i++)
#pragma unroll
        for (int j = 0; j < BN / 32; j++)
          acc[i][j] = mfma16(af[df][i], bfv[df][j], acc[i][j]);
    __builtin_amdgcn_s_setprio(0);
    BARRIER();
  }
#undef STAGE_G
  if constexpr (MODE == 0) {
#pragma unroll
    for (int j = 0; j < 4; j++) {
      int ng = n0 + wc + j * 16 + r;
      int mat = ng >> 10, nn = ng & 1023, hh = nn >> 6, dd = nn & 63;
      const float* bp = mat == 0 ? bias0 : (mat == 1 ? bias1 : bias2);
      short* dst = mat == 0 ? o0 : (mat == 1 ? o1 : o2);
      float bv = bp[nn];
      float sc = (mat == 0) ? 0.18033688f : 1.0f;  // 1/sqrt(D) * log2(e) folded into Q
#pragma unroll
      for (int i = 0; i < 4; i++) {
#pragma unroll
        for (int q = 0; q < 4; q++) {
          int m = m0 + wr + i * 16 + g * 4 + q;
          int bb = m >> 11, ss = m & 2047;
          dst[((size_t)(bb * 16 + hh) * 2048 + ss) * 64 + dd] = f2bs((acc[i][j][q] + bv) * sc);
        }
      }
    }
  } else {
#pragma unroll
    for (int i = 0; i < 4; i++)
#pragma unroll
      for (int q = 0; q < 4; q++) {
        int m = m0 + wr + i * 16 + g * 4 + q;
#pragma unroll
        for (int j = 0; j < 2; j++) {
          int ng = n0 + wc + j * 16 + r;
          fout[(size_t)m * 1024 + ng] = acc[i][j][q] + bias0[ng];
        }
      }
  }
}

// ---------- fused attention: 2 q-tiles/block, KVBLK=128 (R7 structure, known-best) ----------
// Loop1: A(tile0); loop2: B(tile0)+A(tile1) (shared-K QK^T); loop3: B(tile1).
__global__ __launch_bounds__(256, 2)
void attn_kernel(const short* __restrict__ Qm, const short* __restrict__ Km,
                 const short* __restrict__ Vm, float* __restrict__ probs,
                 short* __restrict__ ctx) {
  __shared__ short Ks[2][128 * 64];  // K tiles (32 KB); Q0/Q1 staged here in prologue
  __shared__ short Vt[64 * 136];     // V^T [64 d][128 k + pad], 8-short-unit XOR swizzle
  __shared__ short Ps[4][16 * 136];  // per-wave P bf16 [16 q][128 k] in MFMA-A layout
  __shared__ float rls[128];         // 1/l per q-row (epilogue only; [64..127] = tile1)
  const int f = blockIdx.x;
  const int wgid = (f & 7) * 64 + (f >> 3);      // bijective XCD swizzle (nwg=512)
  const int bh = wgid >> 4, q0 = (wgid & 15) * 128;
  const int bb = bh >> 4, hh = bh & 15;
  const short* Qp = Qm + (size_t)bh * 2048 * 64;
  const short* Kp = Km + (size_t)bh * 2048 * 64;
  const short* Vp = Vm + (size_t)bh * 2048 * 64;
  float* Pp = probs + (size_t)bh * 2048 * 2048;
  const int t = threadIdx.x, w = t >> 6, l = t & 63, g = l >> 4, r = l & 15;
  const int lr = l >> 3, lc = l & 7;
  const int swz = lc ^ lr;  // 16B-unit source swizzle for K/Q staging

#define STAGE_K(kt_, buf_)                                                            \
  do {                                                                                \
    const short* src_ = Kp + (size_t)((kt_) * 128) * 64;                              \
    _Pragma("unroll") for (int it_ = 0; it_ < 4; ++it_)                               \
        gload_lds16(src_ + (size_t)(it_ * 32 + w * 8 + lr) * 64 + swz * 8,            \
                    Ks[buf_] + (it_ * 32 + w * 8) * 64);                              \
  } while (0)

  // ---- prologue: stage Q0 -> Ks[0], Q1 -> Ks[1]; hoist both tiles' fragments ----
#pragma unroll
  for (int it = 0; it < 2; ++it) {
    gload_lds16(Qp + (size_t)(q0 + it * 32 + w * 8 + lr) * 64 + swz * 8,
                Ks[0] + (it * 32 + w * 8) * 64);
    gload_lds16(Qp + (size_t)(q0 + 64 + it * 32 + w * 8 + lr) * 64 + swz * 8,
                Ks[1] + (it * 32 + w * 8) * 64);
  }
  __syncthreads();
  bf16x8 qf0[2], qf1[2];
#pragma unroll
  for (int df = 0; df < 2; df++) {
    qf0[df] = *(const bf16x8*)(Ks[0] + (w * 16 + r) * 64 + ((df * 4 + g) ^ (r & 7)) * 8);
    qf1[df] = *(const bf16x8*)(Ks[1] + (w * 16 + r) * 64 + ((df * 4 + g) ^ (r & 7)) * 8);
  }
  WAIT_LGKM0();
  BARRIER();  // fragments in regs; Ks buffers free

  // -------- loop 1: A(tile0) — row sums of exp2(s), 16 iters --------
  float lrow0 = 0.f;
  STAGE_K(0, 0);
  for (int kt = 0; kt < 16; ++kt) {
    const int cur = kt & 1;
    if (kt < 15) {
      STAGE_K(kt + 1, cur ^ 1);
      WAIT_VMCNT(4);
    } else {
      WAIT_VMCNT(0);
    }
    BARRIER();
    f32x4 st[8] = {};
    __builtin_amdgcn_s_setprio(1);
#pragma unroll
    for (int df = 0; df < 2; ++df) {
      bf16x8 kf[8];
#pragma unroll
      for (int ni = 0; ni < 8; ni++)
        kf[ni] = *(const bf16x8*)(Ks[cur] + (ni * 16 + r) * 64 + ((df * 4 + g) ^ (r & 7)) * 8);
#pragma unroll
      for (int ni = 0; ni < 8; ni++) st[ni] = mfma16(kf[ni], qf0[df], st[ni]);
    }
    __builtin_amdgcn_s_setprio(0);
    float ssum = 0.f;
#pragma unroll
    for (int ni = 0; ni < 8; ni++)
#pragma unroll
      for (int q4 = 0; q4 < 4; q4++) ssum += fexp2(st[ni][q4]);
    ssum += __shfl_xor(ssum, 16);
    ssum += __shfl_xor(ssum, 32);
    lrow0 += ssum;
    BARRIER();  // all waves done reading Ks[cur] before next STAGE overwrites
  }
  const float rinv0 = 1.0f / lrow0;
  if (g == 0) rls[w * 16 + r] = rinv0;

  // V-transpose helper indices: each thread loads 4 V rows (kp,kp+1,kp+64,kp+65)
  const int kp = (t >> 3) * 2, d0v = (t & 7) * 8, lcv = t & 7, kunit = t >> 5;

#define B_TILE_BODY(stv_, qrow_, rinv_)                                                \
  do {                                                                                 \
    /* P = exp2(s): fp32 kept for probs, bf16 copy into Ps */                          \
    _Pragma("unroll") for (int ni = 0; ni < 8; ni++) {                                 \
      bf16x4v pk;                                                                      \
      _Pragma("unroll") for (int q4 = 0; q4 < 4; q4++) {                               \
        float pe = fexp2((stv_)[ni][q4]);                                              \
        (stv_)[ni][q4] = pe;                                                           \
        pk[q4] = f2bs(pe);                                                             \
      }                                                                                \
      *(bf16x4v*)(&Ps[w][r * 136 + ni * 16 + g * 4]) = pk;                             \
    }                                                                                  \
    /* V^T into LDS: unit = (ul&8)|((ul&7)^lcv), ul = k/8 */                           \
    _Pragma("unroll") for (int e = 0; e < 8; e++) {                                    \
      unsigned int p0_ = (unsigned int)(unsigned short)v0[e] |                         \
                         ((unsigned int)(unsigned short)v1[e] << 16);                  \
      unsigned int p1_ = (unsigned int)(unsigned short)v2[e] |                         \
                         ((unsigned int)(unsigned short)v3[e] << 16);                  \
      *(unsigned int*)(Vt + (d0v + e) * 136 + ((kunit ^ lcv) << 3) + (kp & 7)) = p0_;  \
      *(unsigned int*)(Vt + (d0v + e) * 136 + ((8 + (kunit ^ lcv)) << 3) + (kp & 7)) = p1_; \
    }                                                                                  \
    WAIT_LGKM0();                                                                      \
    BARRIER();                                                                         \
    /* probs stores: 8 f32x4/lane, each instr = 16 fully-covered 64B lines */          \
    _Pragma("unroll") for (int ni = 0; ni < 8; ni++) {                                 \
      f32x4 pr;                                                                        \
      _Pragma("unroll") for (int q4 = 0; q4 < 4; q4++) pr[q4] = (stv_)[ni][q4] * (rinv_); \
      *(f32x4*)(Pp + (size_t)((qrow_) + w * 16 + r) * 2048 + kt * 128 + ni * 16 + g * 4) = pr; \
    }                                                                                  \
    /* PV: A = P (own wave rows), B = V^T (cols d), 16 MFMA */                         \
    __builtin_amdgcn_s_setprio(1);                                                     \
    _Pragma("unroll") for (int kf4 = 0; kf4 < 4; ++kf4) {                              \
      bf16x8 pa, vb[4];                                                                \
      pa = *(const bf16x8*)(&Ps[w][r * 136 + kf4 * 32 + g * 8]);                       \
      _Pragma("unroll") for (int nj = 0; nj < 4; nj++) {                               \
        int u_ = kf4 * 4 + g, x_ = nj * 2 + (r >> 3);                                  \
        int su_ = (u_ & 8) | ((u_ & 7) ^ x_);                                          \
        vb[nj] = *(const bf16x8*)(Vt + (nj * 16 + r) * 136 + (su_ << 3));              \
      }                                                                                \
      _Pragma("unroll") for (int nj = 0; nj < 4; nj++)                                 \
          cacc[nj] = mfma16(pa, vb[nj], cacc[nj]);                                     \
    }                                                                                  \
    __builtin_amdgcn_s_setprio(0);                                                     \
  } while (0)

  // -------- loop 2: B(tile0) fused with A(tile1), 16 iters --------
  f32x4 cacc[4] = {};
  float lrow1 = 0.f;
  STAGE_K(0, 0);
  for (int kt = 0; kt < 16; ++kt) {
    const int cur = kt & 1;
    bf16x8 v0 = *(const bf16x8*)(Vp + (size_t)(kt * 128 + kp) * 64 + d0v);
    bf16x8 v1 = *(const bf16x8*)(Vp + (size_t)(kt * 128 + kp + 1) * 64 + d0v);
    bf16x8 v2 = *(const bf16x8*)(Vp + (size_t)(kt * 128 + 64 + kp) * 64 + d0v);
    bf16x8 v3 = *(const bf16x8*)(Vp + (size_t)(kt * 128 + 64 + kp + 1) * 64 + d0v);
    if (kt < 15) STAGE_K(kt + 1, cur ^ 1);
    if (kt == 0) { WAIT_VMCNT(8); }
    else if (kt < 15) { WAIT_VMCNT(16); }
    else { WAIT_VMCNT(12); }
    BARRIER();
    f32x4 st0[8] = {}, st1[8] = {};
    __builtin_amdgcn_s_setprio(1);
#pragma unroll
    for (int df = 0; df < 2; ++df) {
      bf16x8 kf[8];
#pragma unroll
      for (int ni = 0; ni < 8; ni++)
        kf[ni] = *(const bf16x8*)(Ks[cur] + (ni * 16 + r) * 64 + ((df * 4 + g) ^ (r & 7)) * 8);
#pragma unroll
      for (int ni = 0; ni < 8; ni++) {
        st0[ni] = mfma16(kf[ni], qf0[df], st0[ni]);
        st1[ni] = mfma16(kf[ni], qf1[df], st1[ni]);
      }
    }
    __builtin_amdgcn_s_setprio(0);
    {
      float ssum = 0.f;
#pragma unroll
      for (int ni = 0; ni < 8; ni++)
#pragma unroll
        for (int q4 = 0; q4 < 4; q4++) ssum += fexp2(st1[ni][q4]);
      ssum += __shfl_xor(ssum, 16);
      ssum += __shfl_xor(ssum, 32);
      lrow1 += ssum;
    }
    B_TILE_BODY(st0, q0, rinv0);
  }
  // ctx epilogue tile0
#pragma unroll
  for (int nj = 0; nj < 4; nj++)
#pragma unroll
    for (int q4 = 0; q4 < 4; q4++) {
      int qt = w * 16 + g * 4 + q4;
      float val = cacc[nj][q4] * rls[qt];
      ctx[((size_t)(bb * 2048 + q0 + qt)) * 1024 + hh * 64 + nj * 16 + r] = f2bs(val);
    }

  // -------- loop 3: B(tile1), 16 iters --------
  const float rinv1 = 1.0f / lrow1;
  if (g == 0) rls[64 + w * 16 + r] = rinv1;
#pragma unroll
  for (int nj = 0; nj < 4; nj++) cacc[nj] = (f32x4){0.f, 0.f, 0.f, 0.f};
  STAGE_K(0, 0);
  for (int kt = 0; kt < 16; ++kt) {
    const int cur = kt & 1;
    bf16x8 v0 = *(const bf16x8*)(Vp + (size_t)(kt * 128 + kp) * 64 + d0v);
    bf16x8 v1 = *(const bf16x8*)(Vp + (size_t)(kt * 128 + kp + 1) * 64 + d0v);
    bf16x8 v2 = *(const bf16x8*)(Vp + (size_t)(kt * 128 + 64 + kp) * 64 + d0v);
    bf16x8 v3 = *(const bf16x8*)(Vp + (size_t)(kt * 128 + 64 + kp + 1) * 64 + d0v);
    if (kt < 15) STAGE_K(kt + 1, cur ^ 1);
    if (kt == 0) { WAIT_VMCNT(8); }
    else if (kt < 15) { WAIT_VMCNT(16); }
    else { WAIT_VMCNT(12); }
    BARRIER();
    f32x4 st[8] = {};
    __builtin_amdgcn_s_setprio(1);
#pragma unroll
    for (int df = 0; df < 2; ++df) {
      bf16x8 kf[8];
#pragma unroll
      for (int ni = 0; ni < 8; ni++)
        kf[ni] = *(const bf16x8*)(Ks[cur] + (ni * 16 + r) * 64 + ((df * 4 + g) ^ (r & 7)) * 8);
#pragma unroll
      for (int ni = 0; ni < 8; ni++) st[ni] = mfma16(kf[ni], qf1[df], st[ni]);
    }
    __builtin_amdgcn_s_setprio(0);
    B_TILE_BODY(st, q0 + 64, rinv1);
  }
  // ctx epilogue tile1
#pragma unroll
  for (int nj = 0; nj < 4; nj++)
#pragma unroll
    for (int q4 = 0; q4 < 4; q4++) {
      int qt = w * 16 + g * 4 + q4;
      float val = cacc[nj][q4] * rls[64 + qt];
      ctx[((size_t)(bb * 2048 + q0 + 64 + qt)) * 1024 + hh * 64 + nj * 16 + r] = f2bs(val);
    }
#undef B_TILE_BODY
#undef STAGE_K
}

extern "C" void kernel_launch(void* const* d_in, const int* in_sizes, int n_in,
                              void* d_out, int out_size, void* d_ws, size_t ws_size,
                              hipStream_t stream) {
  (void)in_sizes; (void)n_in; (void)out_size; (void)ws_size;
  const float* X  = (const float*)d_in[0];
  const float* Wq = (const float*)d_in[1];
  const float* bq = (const float*)d_in[2];
  const float* Wk = (const float*)d_in[3];
  const float* bk = (const float*)d_in[4];
  const float* Wv = (const float*)d_in[5];
  const float* bv = (const float*)d_in[6];
  const float* Wo = (const float*)d_in[7];
  const float* bo = (const float*)d_in[8];
  float* out = (float*)d_out;
  float* probs = out + (size_t)2 * 2048 * 1024;

  short* Xb = (short*)d_ws;                 // 4096x1024
  short* Wt = Xb + (size_t)4194304;         // 4x1024x1024 (q,k,v,o transposed)
  short* Qb = Wt + (size_t)4194304;         // [B,H,S,D]
  short* Kb = Qb + (size_t)4194304;
  short* Vb = Kb + (size_t)4194304;
  short* Cx = Vb + (size_t)4194304;         // ctx [B,S,E]

  cvt_all_kernel<<<3072, 256, 0, stream>>>(X, Wq, Wk, Wv, Wo, Xb, Wt);
  gemm_bt_kernel<0, 32><<<dim3(32, 24), 256, 0, stream>>>(Xb, Wt, bq, bk, bv,
                                                          Qb, Kb, Vb, nullptr);
  attn_kernel<<<512, 256, 0, stream>>>(Qb, Kb, Vb, probs, Cx);
  gemm_bt_kernel<1, 32><<<dim3(32, 16), 256, 0, stream>>>(Cx, Wt + (size_t)3 * 1048576, bo,
                                                          nullptr, nullptr, nullptr, nullptr,
                                                          nullptr, out);
}